// Round 6
// baseline (489.730 us; speedup 1.0000x reference)
//
#include <hip/hip_runtime.h>

#define BS 16
#define TT 20
#define LL 8
#define STEPS 12
#define NN 512
#define EE 64
#define HS (BS*NN*EE)   // 524288 floats per hidden buffer
#define NPART 311296    // 2*16*19*512
#define NBLK 512

typedef __attribute__((ext_vector_type(8))) short bfrag8;
typedef __attribute__((ext_vector_type(4))) float f32x4;
typedef unsigned short ushort_t;
typedef unsigned int uint_t;

#define MFMA16(a,b,c) __builtin_amdgcn_mfma_f32_16x16x32_bf16(a,b,c,0,0,0)

__device__ __forceinline__ float tanh_fast(float x) {
  float t = __expf(-2.f * fabsf(x));
  float r = (1.f - t) / (1.f + t);
  return copysignf(r, x);
}

__device__ __forceinline__ float lrelu(float x) { return x > 0.f ? x : 0.01f * x; }

__device__ __forceinline__ float wsum64(float x) {
  #pragma unroll
  for (int off = 32; off > 0; off >>= 1) x += __shfl_xor(x, off);
  return x;
}

__device__ __forceinline__ ushort_t f2bf(float f) {   // RNE float->bf16
  uint_t u = __float_as_uint(f);
  u += 0x7fffu + ((u >> 16) & 1u);
  return (ushort_t)(u >> 16);
}

// ---------------------------------------------------------------------------
// Two-level software grid barrier (device-scope).  bar layout (ints):
//   [0..255]  8 arrival counters, 128B apart (bid&7)
//   [256]     mid counter
//   [288]     generation
// Requires all NBLK blocks co-resident (LDS 54KB -> 2 blocks/CU, grid 512).
// ---------------------------------------------------------------------------
__device__ __forceinline__ void grid_barrier(int* bar, int tid, int bid) {
  __syncthreads();
  if (tid == 0) {
    __threadfence();                                   // release prior writes
    int* cnt = bar + (bid & 7) * 32;
    int* mid = bar + 256;
    int* gen = bar + 288;
    int g = __hip_atomic_load(gen, __ATOMIC_RELAXED, __HIP_MEMORY_SCOPE_AGENT);
    if (atomicAdd(cnt, 1) == (NBLK/8) - 1) {           // last in group
      atomicExch(cnt, 0);
      __threadfence();
      if (atomicAdd(mid, 1) == 7) {                    // last group
        atomicExch(mid, 0);
        __threadfence();
        atomicAdd(gen, 1);                             // release
      }
    }
    while (__hip_atomic_load(gen, __ATOMIC_RELAXED, __HIP_MEMORY_SCOPE_AGENT) == g)
      __builtin_amdgcn_s_sleep(1);
    __threadfence();                                   // acquire
  }
  __syncthreads();
}

struct MegaArgs {
  const int *skill, *timeq, *label;
  const float *adj, *nemb;
  const float *W1, *b1, *W2, *b2;
  const float *fw1, *fb1, *g1, *be1;
  const float *fw2, *fb2, *g2, *be2;
  const float *fw3, *fb3;
  float *out, *hbuf, *rows2, *agg_tgt, *partial;
  int *bar;
};

// ===========================================================================
// ONE persistent kernel (plain launch, graph-capture-safe):
//   phase0: stage weights/skill/expdt to LDS; blocks 0..15 init hidden0;
//           all blocks rows2 pass1          -> barrier
//   rows2 pass2                             -> barrier
//   12 fused steps (hidden tile persistent in LDS; hh rows via global
//   ping-pong)                              -> barrier each
//   pred head on blocks 0..95 (384 waves)
// ===========================================================================
__global__ __launch_bounds__(256, 2) void mega_kernel(MegaArgs A)
{
  __shared__ __align__(16) ushort_t sWa[64*72];
  __shared__ __align__(16) ushort_t sWb[64*72];
  __shared__ __align__(16) ushort_t sW2[64*72];
  __shared__ __align__(16) ushort_t sM1[128*72];   // phase-0 alias: float a_s[19*32]
  __shared__ __align__(16) ushort_t sHid[16*72];   // persistent hidden tile (bf16)
  __shared__ __align__(16) ushort_t sHH[16*72];
  __shared__ float sU[8*68];
  __shared__ float sCROW[256];
  __shared__ float sEDall[96];
  __shared__ int   sSK[20];

  int tid = threadIdx.x;
  int bid = blockIdx.x;
  int b  = bid & 15;
  int nt = bid >> 4;
  int nbase = nt * 16;
  int lane = tid & 63;
  int w = tid >> 6;
  int q = lane >> 4, nn = lane & 15;
  int epos = w*16 + nn;

  // ---- phase 0: one-time LDS staging ----
  if (tid < 20) sSK[tid] = A.skill[b*TT + tid];
  if (tid < 96) {
    int s = tid >> 3, l = tid & 7;
    float d = fabsf((float)(A.timeq[b*TT + s + l] - A.timeq[b*TT + s + 8]));
    sEDall[tid] = expf(-logf(d + 1e-6f) * 0.6213349345596119f);
  }
  for (int idx = tid; idx < 4096; idx += 256) {
    int e = idx >> 6, j = idx & 63;
    sWa[e*72 + j] = f2bf(A.W1[e*128 + j]);
    sWb[e*72 + j] = f2bf(A.W1[e*128 + 64 + j]);
    sW2[e*72 + j] = f2bf(A.W2[e*64 + j]);
  }
  __syncthreads();

  // ---- phase 0a (blocks 0..15): zero hidden buffer 0 + hidden0 scatter ----
  if (bid < BS) {
    float4 z4 = make_float4(0.f,0.f,0.f,0.f);
    for (int idx = tid; idx < NN*EE/4; idx += 256)
      *(float4*)&A.hbuf[(size_t)b*NN*EE + idx*4] = z4;
    __syncthreads();
    if (tid < 64) {
      int e = tid;
      for (int l = 0; l < 8; ++l) {
        bool is_last = true;
        for (int l2 = l + 1; l2 < 8; ++l2)
          if (sSK[l2] == sSK[l]) is_last = false;
        if (is_last) {
          float lp = (A.label[b*TT + l] == 1) ? 1.f : -1.f;
          A.hbuf[((size_t)b*NN + sSK[l])*EE + e] = A.nemb[sSK[l]*EE + e] * lp;
        }
      }
    }
  }

  // ---- phase 0b (all blocks): rows2 pass1, 16-way m-split ----
  {
    int kb = bid >> 4;             // 0..31 == k*16+b
    int mc = bid & 15;
    int b0 = kb & 15;
    int m0 = mc * 32;
    float* a_s = (float*)sM1;      // 19*32 floats
    const float* Aa = A.adj + (size_t)kb*NN*NN;
    for (int idx = tid; idx < 19*32; idx += 256) {
      int tt = idx >> 5, mm = idx & 31;
      a_s[idx] = Aa[(size_t)A.skill[b0*TT + tt]*NN + m0 + mm];
    }
    __syncthreads();
    float2 acc[19];
    #pragma unroll
    for (int tt = 0; tt < 19; ++tt) acc[tt] = make_float2(0.f, 0.f);
    int n0 = tid * 2;
    for (int mm0 = 0; mm0 < 32; mm0 += 8) {
      float2 v[8];
      #pragma unroll
      for (int i = 0; i < 8; ++i)
        v[i] = *(const float2*)&Aa[(size_t)(m0 + mm0 + i)*NN + n0];
      #pragma unroll
      for (int tt = 0; tt < 19; ++tt) {
        float4 aa = *(const float4*)&a_s[tt*32 + mm0];
        float4 ab = *(const float4*)&a_s[tt*32 + mm0 + 4];
        acc[tt].x = fmaf(aa.x, v[0].x, acc[tt].x); acc[tt].y = fmaf(aa.x, v[0].y, acc[tt].y);
        acc[tt].x = fmaf(aa.y, v[1].x, acc[tt].x); acc[tt].y = fmaf(aa.y, v[1].y, acc[tt].y);
        acc[tt].x = fmaf(aa.z, v[2].x, acc[tt].x); acc[tt].y = fmaf(aa.z, v[2].y, acc[tt].y);
        acc[tt].x = fmaf(aa.w, v[3].x, acc[tt].x); acc[tt].y = fmaf(aa.w, v[3].y, acc[tt].y);
        acc[tt].x = fmaf(ab.x, v[4].x, acc[tt].x); acc[tt].y = fmaf(ab.x, v[4].y, acc[tt].y);
        acc[tt].x = fmaf(ab.y, v[5].x, acc[tt].x); acc[tt].y = fmaf(ab.y, v[5].y, acc[tt].y);
        acc[tt].x = fmaf(ab.z, v[6].x, acc[tt].x); acc[tt].y = fmaf(ab.z, v[6].y, acc[tt].y);
        acc[tt].x = fmaf(ab.w, v[7].x, acc[tt].x); acc[tt].y = fmaf(ab.w, v[7].y, acc[tt].y);
      }
    }
    float* pbase = A.partial + (size_t)mc * NPART;
    #pragma unroll
    for (int tt = 0; tt < 19; ++tt)
      *(float2*)&pbase[((size_t)kb*19 + tt)*NN + n0] = acc[tt];
  }
  grid_barrier(A.bar, tid, bid);

  // ---- rows2 pass2 ----
  for (int idx = bid*256 + tid; idx < NPART; idx += NBLK*256) {
    float s = 0.f;
    #pragma unroll
    for (int mc = 0; mc < 16; ++mc) s += A.partial[(size_t)mc*NPART + idx];
    A.rows2[idx] = s * (1.f/512.f);
  }
  grid_barrier(A.bar, tid, bid);

  // ---- stage persistent hidden tile (bf16) ----
  for (int idx = tid; idx < 1024; idx += 256) {
    int n = idx >> 6, j = idx & 63;
    sHid[n*72 + j] = f2bf(A.hbuf[((size_t)b*NN + nbase + n)*EE + j]);
  }

  float b1v = A.b1[epos];
  float b2v = A.b2[epos];

  // ---- 12 fused steps ----
  for (int t = 0; t < STEPS; ++t) {
    const float* hsrc = A.hbuf + (size_t)(t & 1) * HS;
    float*       hdst = A.hbuf + (size_t)((t + 1) & 1) * HS;

    for (int idx = tid; idx < 1024; idx += 256) {
      int l = idx >> 6, j = idx & 63;
      ushort_t v = 0;
      if (l < 8) v = f2bf(hsrc[((size_t)b*NN + sSK[t + l])*EE + j]);
      sHH[l*72 + j] = v;
    }
    {
      int k = tid >> 7, l = (tid >> 4) & 7, n = tid & 15;
      int sh = sSK[t + l];
      sCROW[tid] = A.adj[((size_t)(k*BS + b)*NN + sh)*NN + nbase + n]
                 + A.rows2[((size_t)(k*BS + b)*19 + (t + l))*NN + nbase + n];
    }
    __syncthreads();

    // GEMM1: v (Hid @ W1b^T) and u (HH @ W1a^T)
    f32x4 accV = {0.f,0.f,0.f,0.f}, accU = {0.f,0.f,0.f,0.f};
    {
      bfrag8 a0 = *(const bfrag8*)&sHid[nn*72 + q*8];
      bfrag8 a1 = *(const bfrag8*)&sHid[nn*72 + 32 + q*8];
      bfrag8 b0 = *(const bfrag8*)&sWb[epos*72 + q*8];
      bfrag8 b1f = *(const bfrag8*)&sWb[epos*72 + 32 + q*8];
      accV = MFMA16(a0, b0, accV);
      accV = MFMA16(a1, b1f, accV);
      bfrag8 h0 = *(const bfrag8*)&sHH[nn*72 + q*8];
      bfrag8 h1 = *(const bfrag8*)&sHH[nn*72 + 32 + q*8];
      bfrag8 c0 = *(const bfrag8*)&sWa[epos*72 + q*8];
      bfrag8 c1 = *(const bfrag8*)&sWa[epos*72 + 32 + q*8];
      accU = MFMA16(h0, c0, accU);
      accU = MFMA16(h1, c1, accU);
    }
    if (q < 2) {
      #pragma unroll
      for (int r = 0; r < 4; ++r)
        sU[(q*4 + r)*68 + epos] = accU[r] + b1v;
    }
    __syncthreads();

    // m1 = tanh(u + v) -> bf16 LDS (aliases phase-0 a_s region, long dead)
    #pragma unroll
    for (int l = 0; l < 8; ++l) {
      float uu = sU[l*68 + epos];
      #pragma unroll
      for (int r = 0; r < 4; ++r)
        sM1[(l*16 + q*4 + r)*72 + epos] = f2bf(tanh_fast(uu + accV[r]));
    }
    __syncthreads();

    // GEMM2: m2 = m1 @ W2^T
    f32x4 acc2[8];
    #pragma unroll
    for (int l = 0; l < 8; ++l) acc2[l] = (f32x4){0.f,0.f,0.f,0.f};
    {
      bfrag8 w0 = *(const bfrag8*)&sW2[epos*72 + q*8];
      bfrag8 w1 = *(const bfrag8*)&sW2[epos*72 + 32 + q*8];
      #pragma unroll
      for (int l = 0; l < 8; ++l) {
        bfrag8 a0 = *(const bfrag8*)&sM1[(l*16 + nn)*72 + q*8];
        bfrag8 a1 = *(const bfrag8*)&sM1[(l*16 + nn)*72 + 32 + q*8];
        acc2[l] = MFMA16(a0, w0, acc2[l]);
        acc2[l] = MFMA16(a1, w1, acc2[l]);
      }
    }

    // epilogue
    float ag0[4] = {0.f,0.f,0.f,0.f};
    float ag1[4] = {0.f,0.f,0.f,0.f};
    #pragma unroll
    for (int l = 0; l < 8; ++l) {
      float ed = sEDall[t*8 + l];
      #pragma unroll
      for (int r = 0; r < 4; ++r) {
        int m = q*4 + r;
        float qv = tanh_fast(acc2[l][r] + b2v) * ed;
        ag0[r] = fmaf(sCROW[l*16 + m], qv, ag0[r]);
        ag1[r] = fmaf(sCROW[128 + l*16 + m], qv, ag1[r]);
      }
    }
    int tgtn = sSK[t + 8];
    #pragma unroll
    for (int r = 0; r < 4; ++r) {
      int node = nbase + q*4 + r;
      float h = 0.5f * (ag0[r] + ag1[r]);
      hdst[((size_t)b*NN + node)*EE + epos] = h;
      sHid[(q*4 + r)*72 + epos] = f2bf(h);   // local update, no restage
      if (node == tgtn) {
        A.agg_tgt[((t*BS + b)*2 + 0)*EE + epos] = ag0[r];
        A.agg_tgt[((t*BS + b)*2 + 1)*EE + epos] = ag1[r];
      }
    }
    grid_barrier(A.bar, tid, bid);
  }

  // ---- pred: 384 (ts,b,k) rows, one wave each ----
  int wid = (bid << 2) | w;
  if (bid < 96 && wid < 384) {
    int e = lane;
    float x = A.agg_tgt[wid*EE + e];
    float y = A.fb1[e];
    for (int j = 0; j < 64; ++j) y = fmaf(__shfl(x, j), A.fw1[e*64 + j], y);
    float h1 = x + lrelu(y);
    float mean1 = wsum64(h1) * (1.f/64.f);
    float d1 = h1 - mean1;
    float var1 = wsum64(d1*d1) * (1.f/64.f);
    float xn = d1 * rsqrtf(var1 + 1e-5f) * A.g1[e] + A.be1[e];
    float z = A.fb2[e];
    for (int j = 0; j < 64; ++j) z = fmaf(__shfl(xn, j), A.fw2[e*64 + j], z);
    float h2 = h1 + lrelu(z);
    float mean2 = wsum64(h2) * (1.f/64.f);
    float d2 = h2 - mean2;
    float var2 = wsum64(d2*d2) * (1.f/64.f);
    float xn2 = d2 * rsqrtf(var2 + 1e-5f) * A.g2[e] + A.be2[e];
    float p0 = wsum64(xn2 * A.fw3[e]);
    float p1 = wsum64(xn2 * A.fw3[64 + e]);
    if (e == 0) {
      float l0 = p0 + A.fb3[0], l1 = p1 + A.fb3[1];
      A.out[wid] = 1.f / (1.f + expf(l0 - l1));
    }
  }
}

extern "C" void kernel_launch(void* const* d_in, const int* in_sizes, int n_in,
                              void* d_out, int out_size, void* d_ws, size_t ws_size,
                              hipStream_t stream) {
  const int*   skill = (const int*)d_in[0];
  const int*   timeq = (const int*)d_in[1];
  const int*   label = (const int*)d_in[2];
  const float* adj   = (const float*)d_in[3];
  const float* nemb  = (const float*)d_in[4];

  float* ws      = (float*)d_ws;
  float* hbuf    = ws;                       // 2 * 524288
  float* rows2   = ws + 2*HS;                // NPART
  float* agg_tgt = rows2 + NPART;            // 24576
  float* partial = agg_tgt + STEPS*BS*2*EE;  // 16 * NPART
  int*   bar     = (int*)(partial + (size_t)16*NPART);  // 1KB+ barrier state

  MegaArgs a;
  a.skill = skill; a.timeq = timeq; a.label = label;
  a.adj = adj; a.nemb = nemb;
  a.W1 = (const float*)d_in[5];  a.b1 = (const float*)d_in[6];
  a.W2 = (const float*)d_in[7];  a.b2 = (const float*)d_in[8];
  a.fw1 = (const float*)d_in[9]; a.fb1 = (const float*)d_in[10];
  a.g1 = (const float*)d_in[11]; a.be1 = (const float*)d_in[12];
  a.fw2 = (const float*)d_in[13]; a.fb2 = (const float*)d_in[14];
  a.g2 = (const float*)d_in[15]; a.be2 = (const float*)d_in[16];
  a.fw3 = (const float*)d_in[17]; a.fb3 = (const float*)d_in[18];
  a.out = (float*)d_out;
  a.hbuf = hbuf; a.rows2 = rows2; a.agg_tgt = agg_tgt; a.partial = partial;
  a.bar = bar;

  (void)hipMemsetAsync(bar, 0, 2048, stream);   // zero barrier state (poisoned 0xAA)
  mega_kernel<<<NBLK, 256, 0, stream>>>(a);
}

// Round 7
// 391.009 us; speedup vs baseline: 1.2525x; 1.2525x over previous
//
#include <hip/hip_runtime.h>

#define BS 16
#define TT 20
#define STEPS 12
#define NN 512
#define EE 64

typedef __attribute__((ext_vector_type(8))) short bfrag8;
typedef __attribute__((ext_vector_type(4))) float f32x4;
typedef unsigned short ushort_t;
typedef unsigned int uint_t;

#define MFMA16(a,b,c) __builtin_amdgcn_mfma_f32_16x16x32_bf16(a,b,c,0,0,0)

__device__ __forceinline__ float tanh_fast(float x) {
  float t = __expf(-2.f * fabsf(x));
  float r = (1.f - t) / (1.f + t);
  return copysignf(r, x);
}

__device__ __forceinline__ float lrelu(float x) { return x > 0.f ? x : 0.01f * x; }

__device__ __forceinline__ float wsum64(float x) {
  #pragma unroll
  for (int off = 32; off > 0; off >>= 1) x += __shfl_xor(x, off);
  return x;
}

__device__ __forceinline__ ushort_t f2bf(float f) {   // RNE float->bf16
  uint_t u = __float_as_uint(f);
  u += 0x7fffu + ((u >> 16) & 1u);
  return (ushort_t)(u >> 16);
}

// ---------------------------------------------------------------------------
// rows2[kb][t][n] = (1/512) sum_m adj[kb][skill[b,t]][m] * adj[kb][m][n]
// Single pass: grid 256 = kb(32) x nslice(8 of 64 cols). a-rows staged in LDS
// (full 512 m); each thread owns one n-col, m split 4-way across waves, then
// LDS reduce.  adj read exactly once across the grid.
// ---------------------------------------------------------------------------
__global__ __launch_bounds__(256) void rows2_kernel(
    const int* __restrict__ skill, const float* __restrict__ adj,
    float* __restrict__ rows2)
{
  int kb = blockIdx.x >> 3;       // 0..31 = k*16+b
  int ns = blockIdx.x & 7;
  int b = kb & 15;
  int tid = threadIdx.x;
  __shared__ float a_s[19*512];
  __shared__ float red[4*19*64];
  const float* A = adj + (size_t)kb*NN*NN;
  for (int idx = tid; idx < 19*512; idx += 256) {
    int tt = idx >> 9, m = idx & 511;
    a_s[idx] = A[(size_t)skill[b*TT + tt]*NN + m];
  }
  __syncthreads();
  int mg = tid >> 6, nc = tid & 63;
  int n = ns*64 + nc;
  float acc[19];
  #pragma unroll
  for (int t = 0; t < 19; ++t) acc[t] = 0.f;
  int m0 = mg * 128;
  for (int mm = 0; mm < 128; mm += 8) {
    float av[8];
    #pragma unroll
    for (int i = 0; i < 8; ++i) av[i] = A[(size_t)(m0 + mm + i)*NN + n];
    #pragma unroll
    for (int t = 0; t < 19; ++t) {
      float s = acc[t];
      #pragma unroll
      for (int i = 0; i < 8; ++i) s = fmaf(a_s[t*512 + m0 + mm + i], av[i], s);
      acc[t] = s;
    }
  }
  #pragma unroll
  for (int t = 0; t < 19; ++t) red[(mg*19 + t)*64 + nc] = acc[t];
  __syncthreads();
  for (int idx = tid; idx < 19*64; idx += 256) {
    int t = idx >> 6, c = idx & 63;
    float s = red[(0*19 + t)*64 + c] + red[(1*19 + t)*64 + c]
            + red[(2*19 + t)*64 + c] + red[(3*19 + t)*64 + c];
    rows2[((size_t)kb*19 + t)*NN + ns*64 + c] = s * (1.f/512.f);
  }
}

// ---------------------------------------------------------------------------
// crowT[b][t][k][l][j] = adj[k,b,skill[t+l],skill[j]] + rows2[k,b,t+l,skill[j]]
// Tiny scattered-gather table (16*12*2*8*20 floats) for the per-block
// redundant skill-row updates.
// ---------------------------------------------------------------------------
__global__ __launch_bounds__(256) void crowt_kernel(
    const int* __restrict__ skill, const float* __restrict__ adj,
    const float* __restrict__ rows2, float* __restrict__ crowT)
{
  int bt = blockIdx.x;            // 192 = b*12 + t
  int b = bt / STEPS, t = bt % STEPS;
  int tid = threadIdx.x;
  for (int idx = tid; idx < 320; idx += 256) {
    int k = idx / 160, rem = idx % 160, l = rem / 20, j = rem % 20;
    int shl = skill[b*TT + t + l];
    int nj  = skill[b*TT + j];
    crowT[(size_t)bt*320 + idx] =
        adj[((size_t)(k*BS + b)*NN + shl)*NN + nj]
      + rows2[((size_t)(k*BS + b)*19 + (t + l))*NN + nj];
  }
}

struct FArgs {
  const int *skill, *timeq, *label;
  const float *adj, *nemb;
  const float *W1, *b1, *W2, *b2;
  const float *fw1, *fb1, *g1, *be1;
  const float *fw2, *fb2, *g2, *be2;
  const float *fw3, *fb3;
  const float *rows2, *crowT;
  float *out;
};

__device__ __forceinline__ float init_hidden_val(
    const int* sk, const FArgs& A, int b, int n, int e)
{
  float v = 0.f;
  for (int l = 0; l < 8; ++l)
    if (sk[l] == n)    // last match wins == is_last semantics
      v = A.nemb[n*EE + e] * ((A.label[b*TT + l] == 1) ? 1.f : -1.f);
  return v;
}

// ===========================================================================
// Fused 12-step kernel.  Grid 512 = b(16) x ntile(32 of 16 nodes), 256 thr.
// No cross-block communication: each block keeps (a) its 16-row hidden tile
// and (b) a redundant copy of hidden at all 20 skill positions (sHS) in LDS,
// updating both each step.  hh rows for step t+1 are sHS[t+1..t+8] — local.
// GEMM2 row layout j'*4+l2 (j' = 16 main n + 20 ext skill rows = 36) makes
// the l-sum lane-local (jp = 4g+q).  Pred fused: block nt==t predicts step t.
// ===========================================================================
__global__ __launch_bounds__(256) void fused_kernel(FArgs A)
{
  __shared__ __align__(16) ushort_t sWa[64*72];
  __shared__ __align__(16) ushort_t sWb[64*72];
  __shared__ __align__(16) ushort_t sW2s[64*72];
  __shared__ __align__(16) ushort_t sM1[144*72];
  __shared__ __align__(16) ushort_t sHid[16*72];
  __shared__ __align__(16) ushort_t sHS[32*72];
  __shared__ float sU[8*72];
  __shared__ float sCROW[256];    // [k][l][n16]
  __shared__ float sCT[320];      // [k][l][j20]
  __shared__ float sED[96];
  __shared__ float sPD[128];      // pred input rows (k=2 x 64), step nt only
  __shared__ int   sSK[TT];

  int tid = threadIdx.x, bid = blockIdx.x;
  int b = bid & 15, nt = bid >> 4, nbase = nt*16;
  int lane = tid & 63, w = tid >> 6, q = lane >> 4, nn = lane & 15;
  int epos = w*16 + nn;

  if (tid < TT) sSK[tid] = A.skill[b*TT + tid];
  if (tid < 96) {
    int s = tid >> 3, l = tid & 7;
    float d = fabsf((float)(A.timeq[b*TT + s + l] - A.timeq[b*TT + s + 8]));
    sED[tid] = expf(-logf(d + 1e-6f) * 0.6213349345596119f);
  }
  for (int idx = tid; idx < 4096; idx += 256) {
    int e = idx >> 6, j = idx & 63;
    sWa[e*72 + j]  = f2bf(A.W1[e*128 + j]);
    sWb[e*72 + j]  = f2bf(A.W1[e*128 + 64 + j]);
    sW2s[e*72 + j] = f2bf(A.W2[e*64 + j]);
  }
  __syncthreads();                 // sSK ready for init

  for (int idx = tid; idx < 1024; idx += 256) {
    int nl = idx >> 6, e = idx & 63;
    sHid[nl*72 + e] = f2bf(init_hidden_val(sSK, A, b, nbase + nl, e));
  }
  for (int idx = tid; idx < 2048; idx += 256) {
    int j = idx >> 6, e = idx & 63;
    sHS[j*72 + e] = (j < TT) ? f2bf(init_hidden_val(sSK, A, b, sSK[j], e))
                             : (ushort_t)0;
  }
  __syncthreads();

  float b1v = A.b1[epos], b2v = A.b2[epos];

  for (int t = 0; t < STEPS; ++t) {
    // ---- stage crow (main tile) + crowT (ext skill cols) ----
    {
      int k = tid >> 7, l = (tid >> 4) & 7, n = tid & 15;
      sCROW[tid] = A.adj[((size_t)(k*BS + b)*NN + sSK[t + l])*NN + nbase + n]
                 + A.rows2[((size_t)(k*BS + b)*19 + (t + l))*NN + nbase + n];
    }
    for (int idx = tid; idx < 320; idx += 256)
      sCT[idx] = A.crowT[(size_t)(b*STEPS + t)*320 + idx];

    // ---- GEMM1: v_main (sHid), v_ext x2 (sHS), u (sHS rows t..t+15) ----
    f32x4 accU = {0,0,0,0}, accVm = {0,0,0,0};
    f32x4 accVe0 = {0,0,0,0}, accVe1 = {0,0,0,0};
    {
      bfrag8 b0  = *(const bfrag8*)&sWb[epos*72 + q*8];
      bfrag8 b1f = *(const bfrag8*)&sWb[epos*72 + 32 + q*8];
      bfrag8 c0  = *(const bfrag8*)&sWa[epos*72 + q*8];
      bfrag8 c1  = *(const bfrag8*)&sWa[epos*72 + 32 + q*8];

      bfrag8 a0 = *(const bfrag8*)&sHid[nn*72 + q*8];
      bfrag8 a1 = *(const bfrag8*)&sHid[nn*72 + 32 + q*8];
      accVm = MFMA16(a0, b0, accVm);  accVm = MFMA16(a1, b1f, accVm);

      bfrag8 e00 = *(const bfrag8*)&sHS[nn*72 + q*8];
      bfrag8 e01 = *(const bfrag8*)&sHS[nn*72 + 32 + q*8];
      accVe0 = MFMA16(e00, b0, accVe0);  accVe0 = MFMA16(e01, b1f, accVe0);

      bfrag8 e10 = *(const bfrag8*)&sHS[(16 + nn)*72 + q*8];
      bfrag8 e11 = *(const bfrag8*)&sHS[(16 + nn)*72 + 32 + q*8];
      accVe1 = MFMA16(e10, b0, accVe1);  accVe1 = MFMA16(e11, b1f, accVe1);

      bfrag8 h0 = *(const bfrag8*)&sHS[(t + nn)*72 + q*8];
      bfrag8 h1 = *(const bfrag8*)&sHS[(t + nn)*72 + 32 + q*8];
      accU = MFMA16(h0, c0, accU);  accU = MFMA16(h1, c1, accU);
    }
    if (q < 2) {
      #pragma unroll
      for (int r = 0; r < 4; ++r) sU[(q*4 + r)*72 + epos] = accU[r] + b1v;
    }
    __syncthreads();

    float agg[9][2];
    #pragma unroll
    for (int g = 0; g < 9; ++g) agg[g][0] = agg[g][1] = 0.f;

    #pragma unroll
    for (int h = 0; h < 2; ++h) {
      // ---- m1 half: rows j'*4+l2 (j'<16 main, 16..35 ext), q-staggered l2 ----
      #pragma unroll
      for (int l2i = 0; l2i < 4; ++l2i) {
        int l2 = (l2i + q) & 3;
        float uu = sU[(4*h + l2)*72 + epos];
        #pragma unroll
        for (int r = 0; r < 4; ++r) {
          sM1[((q*4 + r)*4 + l2)*72 + epos]        = f2bf(tanh_fast(uu + accVm[r]));
          sM1[((16 + q*4 + r)*4 + l2)*72 + epos]   = f2bf(tanh_fast(uu + accVe0[r]));
        }
        if (q == 0) {
          #pragma unroll
          for (int r = 0; r < 4; ++r)
            sM1[((32 + r)*4 + l2)*72 + epos]       = f2bf(tanh_fast(uu + accVe1[r]));
        }
      }
      __syncthreads();             // m1 ready

      // ---- GEMM2 half: 9 groups of 16 rows ----
      bfrag8 w0 = *(const bfrag8*)&sW2s[epos*72 + q*8];
      bfrag8 w1 = *(const bfrag8*)&sW2s[epos*72 + 32 + q*8];
      f32x4 acc2[9];
      #pragma unroll
      for (int g = 0; g < 9; ++g) {
        bfrag8 a0 = *(const bfrag8*)&sM1[(16*g + nn)*72 + q*8];
        bfrag8 a1 = *(const bfrag8*)&sM1[(16*g + nn)*72 + 32 + q*8];
        f32x4 z = {0,0,0,0};
        z = MFMA16(a0, w0, z);
        z = MFMA16(a1, w1, z);
        acc2[g] = z;
      }
      // ---- accumulate (lane-local l-sum: jp = 4g+q, reg r = l2) ----
      #pragma unroll
      for (int g = 0; g < 9; ++g) {
        int jp = 4*g + q;
        #pragma unroll
        for (int r = 0; r < 4; ++r) {
          int l = 4*h + r;
          float m2 = tanh_fast(acc2[g][r] + b2v) * sED[t*8 + l];
          float c0, c1;
          if (jp < 16) { c0 = sCROW[l*16 + jp];       c1 = sCROW[128 + l*16 + jp]; }
          else         { c0 = sCT[l*20 + (jp - 16)];  c1 = sCT[160 + l*20 + (jp - 16)]; }
          agg[g][0] = fmaf(c0, m2, agg[g][0]);
          agg[g][1] = fmaf(c1, m2, agg[g][1]);
        }
      }
      __syncthreads();             // before next half overwrites sM1
    }

    // ---- epilogue: update sHid / sHS; stash pred row at nt==t ----
    #pragma unroll
    for (int g = 0; g < 9; ++g) {
      int jp = 4*g + q;
      float hm = 0.5f * (agg[g][0] + agg[g][1]);
      if (jp < 16) {
        sHid[jp*72 + epos] = f2bf(hm);
      } else {
        sHS[(jp - 16)*72 + epos] = f2bf(hm);
        if (nt == t && jp == t + 24) {       // jp-16 == t+8 (= tgt position)
          sPD[epos]      = agg[g][0];
          sPD[64 + epos] = agg[g][1];
        }
      }
    }
    __syncthreads();
  }

  // ---- pred: block nt (0..11) predicts its step, waves 0/1 = k 0/1 ----
  if (nt < STEPS && w < 2) {
    int k = w, e = lane;
    float x = sPD[k*64 + e];
    float y = A.fb1[e];
    for (int j = 0; j < 64; ++j) y = fmaf(__shfl(x, j), A.fw1[e*64 + j], y);
    float h1 = x + lrelu(y);
    float mean1 = wsum64(h1) * (1.f/64.f);
    float d1 = h1 - mean1;
    float var1 = wsum64(d1*d1) * (1.f/64.f);
    float xn = d1 * rsqrtf(var1 + 1e-5f) * A.g1[e] + A.be1[e];
    float z = A.fb2[e];
    for (int j = 0; j < 64; ++j) z = fmaf(__shfl(xn, j), A.fw2[e*64 + j], z);
    float h2 = h1 + lrelu(z);
    float mean2 = wsum64(h2) * (1.f/64.f);
    float d2 = h2 - mean2;
    float var2 = wsum64(d2*d2) * (1.f/64.f);
    float xn2 = d2 * rsqrtf(var2 + 1e-5f) * A.g2[e] + A.be2[e];
    float p0 = wsum64(xn2 * A.fw3[e]);
    float p1 = wsum64(xn2 * A.fw3[64 + e]);
    if (e == 0) {
      float l0 = p0 + A.fb3[0], l1 = p1 + A.fb3[1];
      A.out[(nt*BS + b)*2 + k] = 1.f / (1.f + expf(l0 - l1));
    }
  }
}

extern "C" void kernel_launch(void* const* d_in, const int* in_sizes, int n_in,
                              void* d_out, int out_size, void* d_ws, size_t ws_size,
                              hipStream_t stream) {
  const int*   skill = (const int*)d_in[0];
  const float* adj   = (const float*)d_in[3];

  float* ws    = (float*)d_ws;
  float* rows2 = ws;                           // 32*19*512 = 311296 floats
  float* crowT = ws + 311296;                  // 192*320  = 61440 floats

  rows2_kernel<<<256, 256, 0, stream>>>(skill, adj, rows2);
  crowt_kernel<<<192, 256, 0, stream>>>(skill, adj, rows2, crowT);

  FArgs a;
  a.skill = skill;
  a.timeq = (const int*)d_in[1];
  a.label = (const int*)d_in[2];
  a.adj = adj;
  a.nemb = (const float*)d_in[4];
  a.W1 = (const float*)d_in[5];   a.b1 = (const float*)d_in[6];
  a.W2 = (const float*)d_in[7];   a.b2 = (const float*)d_in[8];
  a.fw1 = (const float*)d_in[9];  a.fb1 = (const float*)d_in[10];
  a.g1 = (const float*)d_in[11];  a.be1 = (const float*)d_in[12];
  a.fw2 = (const float*)d_in[13]; a.fb2 = (const float*)d_in[14];
  a.g2 = (const float*)d_in[15];  a.be2 = (const float*)d_in[16];
  a.fw3 = (const float*)d_in[17]; a.fb3 = (const float*)d_in[18];
  a.rows2 = rows2; a.crowT = crowT;
  a.out = (float*)d_out;

  fused_kernel<<<512, 256, 0, stream>>>(a);
}

// Round 8
// 234.343 us; speedup vs baseline: 2.0898x; 1.6685x over previous
//
#include <hip/hip_runtime.h>
#include <hip/hip_bf16.h>

#define BS 16
#define TT 20
#define STEPS 12
#define NN 512
#define EE 64
#define HS (BS*NN*EE)

typedef __attribute__((ext_vector_type(8))) short bfrag8;
typedef __attribute__((ext_vector_type(4))) float f32x4;
typedef unsigned short ushort_t;
typedef unsigned int uint_t;

#define MFMA16(a,b,c) __builtin_amdgcn_mfma_f32_16x16x32_bf16(a,b,c,0,0,0)

#if __has_builtin(__builtin_amdgcn_rcpf)
#define RCP(x) __builtin_amdgcn_rcpf(x)
#else
#define RCP(x) (1.0f/(x))
#endif

__device__ __forceinline__ float tanh_fast(float x) {
  float t = __expf(-2.f * fabsf(x));      // in (0,1]
  float r = (1.f - t) * RCP(1.f + t);
  return copysignf(r, x);
}

__device__ __forceinline__ float lrelu(float x) { return x > 0.f ? x : 0.01f * x; }

__device__ __forceinline__ float wsum64(float x) {
  #pragma unroll
  for (int off = 32; off > 0; off >>= 1) x += __shfl_xor(x, off);
  return x;
}

__device__ __forceinline__ ushort_t f2bf(float f) {   // RNE float->bf16
  uint_t u = __float_as_uint(f);
  u += 0x7fffu + ((u >> 16) & 1u);
  return (ushort_t)(u >> 16);
}

// ===========================================================================
// setup kernel, grid 273:
//  bid<256  : rows2[kb][t][n] = (1/512) sum_m adj[kb][sk[t]][m] adj[kb][m][n]
//  256..271 : zero hbuf0[b], scatter hidden0, expdt -> global
//  272      : W1a/W1b/W2 -> bf16 wbuf
// ===========================================================================
__global__ __launch_bounds__(256) void setup_kernel(
    const int* __restrict__ skill, const int* __restrict__ timeq,
    const int* __restrict__ label, const float* __restrict__ adj,
    const float* __restrict__ nemb,
    const float* __restrict__ W1, const float* __restrict__ W2,
    float* __restrict__ rows2, float* __restrict__ hbuf,
    float* __restrict__ expdt, ushort_t* __restrict__ wbuf)
{
  __shared__ float a_s[19*512];
  __shared__ float red[4*19*64];
  int tid = threadIdx.x, bid = blockIdx.x;

  if (bid < 256) {
    int kb = bid >> 3;       // 0..31 = k*16+b
    int ns = bid & 7;
    int b = kb & 15;
    const float* A = adj + (size_t)kb*NN*NN;
    for (int idx = tid; idx < 19*512; idx += 256) {
      int tt = idx >> 9, m = idx & 511;
      a_s[idx] = A[(size_t)skill[b*TT + tt]*NN + m];
    }
    __syncthreads();
    int mg = tid >> 6, nc = tid & 63;
    int n = ns*64 + nc;
    float acc[19];
    #pragma unroll
    for (int t = 0; t < 19; ++t) acc[t] = 0.f;
    int m0 = mg * 128;
    for (int mm = 0; mm < 128; mm += 8) {
      float av[8];
      #pragma unroll
      for (int i = 0; i < 8; ++i) av[i] = A[(size_t)(m0 + mm + i)*NN + n];
      #pragma unroll
      for (int t = 0; t < 19; ++t) {
        float s = acc[t];
        #pragma unroll
        for (int i = 0; i < 8; ++i) s = fmaf(a_s[t*512 + m0 + mm + i], av[i], s);
        acc[t] = s;
      }
    }
    #pragma unroll
    for (int t = 0; t < 19; ++t) red[(mg*19 + t)*64 + nc] = acc[t];
    __syncthreads();
    for (int idx = tid; idx < 19*64; idx += 256) {
      int t = idx >> 6, c = idx & 63;
      float s = red[(0*19 + t)*64 + c] + red[(1*19 + t)*64 + c]
              + red[(2*19 + t)*64 + c] + red[(3*19 + t)*64 + c];
      rows2[((size_t)kb*19 + t)*NN + ns*64 + c] = s * (1.f/512.f);
    }
  } else if (bid < 272) {
    int b = bid - 256;
    float4 z4 = make_float4(0.f,0.f,0.f,0.f);
    for (int idx = tid; idx < NN*EE/4; idx += 256)
      *(float4*)&hbuf[(size_t)b*NN*EE + idx*4] = z4;
    __syncthreads();
    if (tid < 64) {
      int e = tid;
      for (int l = 0; l < 8; ++l) {
        bool is_last = true;
        for (int l2 = l + 1; l2 < 8; ++l2)
          if (skill[b*TT + l2] == skill[b*TT + l]) is_last = false;
        if (is_last) {
          int s0 = skill[b*TT + l];
          float lp = (label[b*TT + l] == 1) ? 1.f : -1.f;
          hbuf[((size_t)b*NN + s0)*EE + e] = nemb[s0*EE + e] * lp;
        }
      }
    }
    for (int idx = tid; idx < STEPS*8; idx += 256) {
      int s = idx >> 3, l = idx & 7;
      float d = fabsf((float)(timeq[b*TT + s + l] - timeq[b*TT + s + 8]));
      expdt[(b*STEPS + s)*8 + l] = expf(-logf(d + 1e-6f) * 0.6213349345596119f);
    }
  } else {
    // weights: [0..4096) Wa, [4096..8192) Wb, [8192..12288) W2 (row e, col j)
    for (int idx = tid; idx < 4096; idx += 256) {
      int e = idx >> 6, j = idx & 63;
      wbuf[idx]        = f2bf(W1[e*128 + j]);
      wbuf[4096 + idx] = f2bf(W1[e*128 + 64 + j]);
      wbuf[8192 + idx] = f2bf(W2[e*64 + j]);
    }
  }
}

// ===========================================================================
// Per-step kernel.  Grid 1024 = b(16) x nt(64 tiles of 8 nodes), 256 thr,
// 4 blocks/CU.  Own 8-node hidden tile persists in LDS (sHH rows 0..7);
// hh rows (8..15) restaged from the global ping-pong each step.
// GEMM1 (one MFMA A = [own8 ; hh8], B = W1b then W1a) -> tanh(v), tanh(u)
// in f32 LDS; m1 built by the pair-vectorized Pade pass
// tanh(u+v) = (tu+tv)/(1+tu*tv); GEMM2 (4 groups) -> m2 tanh -> agg.
// ===========================================================================
__global__ __launch_bounds__(256, 4) void step_kernel(
    const float* __restrict__ hsrc, float* __restrict__ hdst,
    const float* __restrict__ adj, const float* __restrict__ rows2,
    const float* __restrict__ expdt, const int* __restrict__ skill,
    const ushort_t* __restrict__ wbuf,
    const float* __restrict__ b1, const float* __restrict__ b2,
    float* __restrict__ agg_tgt, int t)
{
  __shared__ __align__(16) ushort_t sWb[64*72];   // W1b (B for v) - staged once
  __shared__ __align__(16) ushort_t sWx[64*72];   // W1a (phase1) / W2 (phase2)
  __shared__ __align__(16) ushort_t sM1[64*72];
  __shared__ __align__(16) ushort_t sHH[16*72];   // rows0-7 own tile, 8-15 hh
  __shared__ float sTV[8*72];
  __shared__ float sTU[8*72];
  __shared__ float sCROW[128];                    // [k][l][n8]
  __shared__ float sED[8];
  __shared__ int   sSK[TT];

  int tid = threadIdx.x, bid = blockIdx.x;
  int b = bid & 15, nt = bid >> 4, nbase = nt * 8;
  int lane = tid & 63, w = tid >> 6, q = lane >> 4, nn = lane & 15;
  int epos = w*16 + nn;

  if (tid < TT) sSK[tid] = skill[b*TT + tid];
  if (tid < 8)  sED[tid] = expdt[(b*STEPS + t)*8 + tid];
  // Wb once (512 uint4)
  {
    const uint4* src = (const uint4*)(wbuf + 4096);
    for (int idx = tid; idx < 512; idx += 256)
      *(uint4*)&sWb[(idx >> 3)*72 + (idx & 7)*8] = src[idx];
  }
  // Wa (phase 1)
  {
    const uint4* src = (const uint4*)wbuf;
    for (int idx = tid; idx < 512; idx += 256)
      *(uint4*)&sWx[(idx >> 3)*72 + (idx & 7)*8] = src[idx];
  }
  // own tile rows 0..7 (hsrc holds current hidden)
  for (int idx = tid; idx < 512; idx += 256) {
    int n = idx >> 6, e = idx & 63;
    sHH[n*72 + e] = f2bf(hsrc[((size_t)b*NN + nbase + n)*EE + e]);
  }
  __syncthreads();                 // sSK visible for hh staging

  // hh rows 8..15 + crow
  for (int idx = tid; idx < 512; idx += 256) {
    int l = idx >> 6, e = idx & 63;
    sHH[(8 + l)*72 + e] = f2bf(hsrc[((size_t)b*NN + sSK[t + l])*EE + e]);
  }
  if (tid < 128) {
    int k = tid >> 6, l = (tid >> 3) & 7, n = tid & 7;
    sCROW[tid] = adj[((size_t)(k*BS + b)*NN + sSK[t + l])*NN + nbase + n]
               + rows2[((size_t)(k*BS + b)*19 + (t + l))*NN + nbase + n];
  }
  __syncthreads();

  float b1v = b1[epos], b2v = b2[epos];

  // ---- GEMM1: D1 = [own;hh] @ W1b^T (rows0-7 = v), D2 = @ W1a^T (rows8-15 = u)
  f32x4 accV = {0,0,0,0}, accU = {0,0,0,0};
  {
    bfrag8 a0 = *(const bfrag8*)&sHH[nn*72 + q*8];
    bfrag8 a1 = *(const bfrag8*)&sHH[nn*72 + 32 + q*8];
    bfrag8 b0 = *(const bfrag8*)&sWb[epos*72 + q*8];
    bfrag8 b1f = *(const bfrag8*)&sWb[epos*72 + 32 + q*8];
    accV = MFMA16(a0, b0, accV);  accV = MFMA16(a1, b1f, accV);
    bfrag8 c0 = *(const bfrag8*)&sWx[epos*72 + q*8];
    bfrag8 c1 = *(const bfrag8*)&sWx[epos*72 + 32 + q*8];
    accU = MFMA16(a0, c0, accU);  accU = MFMA16(a1, c1, accU);
  }
  if (q < 2) {                     // D rows q*4+r = nodes 0..7 -> tanh(v)
    #pragma unroll
    for (int r = 0; r < 4; ++r)
      sTV[(q*4 + r)*72 + epos] = tanh_fast(accV[r]);
  } else {                         // D rows q*4+r-8 = l 0..7 -> tanh(u+b1)
    #pragma unroll
    for (int r = 0; r < 4; ++r)
      sTU[((q - 2)*4 + r)*72 + epos] = tanh_fast(accU[r] + b1v);
  }
  __syncthreads();

  // ---- phase 2: W2 -> sWx (overwrites Wa) ; m1 Pade pass (independent)
  {
    const uint4* src = (const uint4*)(wbuf + 8192);
    for (int idx = tid; idx < 512; idx += 256)
      *(uint4*)&sWx[(idx >> 3)*72 + (idx & 7)*8] = src[idx];
  }
  {
    int n  = tid >> 5;             // 0..7, fixed per thread
    int ep = tid & 31;             // e-pair
    float2 tv2 = *(const float2*)&sTV[n*72 + 2*ep];
    #pragma unroll
    for (int i = 0; i < 8; ++i) {  // l = i ; row = i*8 + n
      float2 tu2 = *(const float2*)&sTU[i*72 + 2*ep];
      float2 num, den;
      num.x = tu2.x + tv2.x;            num.y = tu2.y + tv2.y;
      den.x = fmaf(tu2.x, tv2.x, 1.f);  den.y = fmaf(tu2.y, tv2.y, 1.f);
      den.x = fmaxf(den.x, 1e-30f);     den.y = fmaxf(den.y, 1e-30f);
      float2 m;
      m.x = num.x * RCP(den.x);         m.y = num.y * RCP(den.y);
      __hip_bfloat162 h2 = __float22bfloat162_rn(m);
      *(__hip_bfloat162*)&sM1[(i*8 + n)*72 + 2*ep] = h2;
    }
  }
  __syncthreads();

  // ---- GEMM2: m2 = m1 @ W2^T, 4 groups of 16 rows; tanh, ed, crow-agg
  float ag0[4] = {0,0,0,0}, ag1[4] = {0,0,0,0};
  {
    bfrag8 w0 = *(const bfrag8*)&sWx[epos*72 + q*8];
    bfrag8 w1 = *(const bfrag8*)&sWx[epos*72 + 32 + q*8];
    #pragma unroll
    for (int g = 0; g < 4; ++g) {
      bfrag8 a0 = *(const bfrag8*)&sM1[(16*g + nn)*72 + q*8];
      bfrag8 a1 = *(const bfrag8*)&sM1[(16*g + nn)*72 + 32 + q*8];
      f32x4 z = {0,0,0,0};
      z = MFMA16(a0, w0, z);
      z = MFMA16(a1, w1, z);
      int l = 2*g + (q >> 1);      // sM1 row 16g+4q+r -> l = row>>3
      float ed = sED[l];
      #pragma unroll
      for (int r = 0; r < 4; ++r) {
        int n = 4*(q & 1) + r;     // row&7
        float m2 = tanh_fast(z[r] + b2v) * ed;
        ag0[r] = fmaf(sCROW[l*8 + n], m2, ag0[r]);
        ag1[r] = fmaf(sCROW[64 + l*8 + n], m2, ag1[r]);
      }
    }
  }
  // combine the two l-parity lanes (q <-> q^2 is lane^32)
  #pragma unroll
  for (int r = 0; r < 4; ++r) {
    ag0[r] += __shfl_xor(ag0[r], 32);
    ag1[r] += __shfl_xor(ag1[r], 32);
  }
  int tgtn = sSK[t + 8];
  if (q < 2) {                     // q in {0,1}: n = 4q+r covers 0..7
    #pragma unroll
    for (int r = 0; r < 4; ++r) {
      int n = 4*q + r;
      int node = nbase + n;
      float h = 0.5f * (ag0[r] + ag1[r]);
      hdst[((size_t)b*NN + node)*EE + epos] = h;
      if (node == tgtn) {
        agg_tgt[((t*BS + b)*2 + 0)*EE + epos] = ag0[r];
        agg_tgt[((t*BS + b)*2 + 1)*EE + epos] = ag1[r];
      }
    }
  }
}

// ===========================================================================
// Head: 3 linears + 2 layernorms + softmax[...,1] on the 384 gathered rows.
// ===========================================================================
__global__ __launch_bounds__(64) void pred_kernel(
    const float* __restrict__ agg_tgt,
    const float* __restrict__ fw1, const float* __restrict__ fb1,
    const float* __restrict__ g1, const float* __restrict__ be1,
    const float* __restrict__ fw2, const float* __restrict__ fb2,
    const float* __restrict__ g2, const float* __restrict__ be2,
    const float* __restrict__ fw3, const float* __restrict__ fb3,
    float* __restrict__ out)
{
  int ts = blockIdx.x >> 4, b = blockIdx.x & 15;
  int e = threadIdx.x;
  __shared__ float sx[64];
  for (int k = 0; k < 2; ++k) {
    float x = agg_tgt[((ts*BS + b)*2 + k)*EE + e];
    sx[e] = x;
    __syncthreads();
    float y = fb1[e];
    for (int j = 0; j < 64; ++j) y = fmaf(sx[j], fw1[e*64 + j], y);
    float h1 = x + lrelu(y);
    float mean1 = wsum64(h1) * (1.f/64.f);
    float d1 = h1 - mean1;
    float var1 = wsum64(d1*d1) * (1.f/64.f);
    float xn = d1 * rsqrtf(var1 + 1e-5f) * g1[e] + be1[e];
    __syncthreads();
    sx[e] = xn;
    __syncthreads();
    float z = fb2[e];
    for (int j = 0; j < 64; ++j) z = fmaf(sx[j], fw2[e*64 + j], z);
    float h2 = h1 + lrelu(z);
    float mean2 = wsum64(h2) * (1.f/64.f);
    float d2 = h2 - mean2;
    float var2 = wsum64(d2*d2) * (1.f/64.f);
    float xn2 = d2 * rsqrtf(var2 + 1e-5f) * g2[e] + be2[e];
    float p0 = wsum64(xn2 * fw3[e]);
    float p1 = wsum64(xn2 * fw3[64 + e]);
    if (e == 0) {
      float l0 = p0 + fb3[0], l1 = p1 + fb3[1];
      out[(ts*BS + b)*2 + k] = 1.f / (1.f + expf(l0 - l1));
    }
    __syncthreads();
  }
}

extern "C" void kernel_launch(void* const* d_in, const int* in_sizes, int n_in,
                              void* d_out, int out_size, void* d_ws, size_t ws_size,
                              hipStream_t stream) {
  const int*   skill = (const int*)d_in[0];
  const int*   timeq = (const int*)d_in[1];
  const int*   label = (const int*)d_in[2];
  const float* adj   = (const float*)d_in[3];
  const float* nemb  = (const float*)d_in[4];
  const float* W1    = (const float*)d_in[5];
  const float* b1    = (const float*)d_in[6];
  const float* W2    = (const float*)d_in[7];
  const float* b2    = (const float*)d_in[8];
  float* out = (float*)d_out;

  float* ws      = (float*)d_ws;
  float* hbuf    = ws;                       // 2 * 524288
  float* rows2   = ws + 2*HS;                // 311296
  float* expdt   = rows2 + 32*19*NN;         // 1536
  float* agg_tgt = expdt + BS*STEPS*8;       // 24576
  ushort_t* wbuf = (ushort_t*)(agg_tgt + STEPS*BS*2*EE);  // 12288 ush

  setup_kernel<<<273, 256, 0, stream>>>(skill, timeq, label, adj, nemb,
                                        W1, W2, rows2, hbuf, expdt, wbuf);

  for (int t = 0; t < STEPS; ++t) {
    const float* hsrc = hbuf + (size_t)(t & 1) * HS;
    float*       hdst = hbuf + (size_t)((t + 1) & 1) * HS;
    step_kernel<<<1024, 256, 0, stream>>>(hsrc, hdst, adj, rows2, expdt, skill,
                                          wbuf, b1, b2, agg_tgt, t);
  }
  pred_kernel<<<STEPS*BS, 64, 0, stream>>>(agg_tgt,
      (const float*)d_in[9],  (const float*)d_in[10],
      (const float*)d_in[11], (const float*)d_in[12],
      (const float*)d_in[13], (const float*)d_in[14],
      (const float*)d_in[15], (const float*)d_in[16],
      (const float*)d_in[17], (const float*)d_in[18], out);
}